// Round 7
// baseline (4656.920 us; speedup 1.0000x reference)
//
#include <hip/hip_runtime.h>
#include <stdint.h>

#define Bsz  128
#define NUMS 128
#define SEQn 256
#define Hn   1024
#define PRED 96
#define G4H  4096
#define GN   256            // persistent grid: 256 blocks = 64 nb x 4 mb (1 per CU)
#define BH   ((size_t)Bsz*Hn)

typedef __attribute__((ext_vector_type(8))) short bf16x8;
typedef __attribute__((ext_vector_type(4))) float f32x4;

template<int N> struct IC { static constexpr int value = N; };

__device__ __forceinline__ unsigned short f2bf(float x){
  union { float f; unsigned u; } v; v.f = x;
  return (unsigned short)((v.u + 0x7FFFu + ((v.u >> 16) & 1u)) >> 16);
}

// counted-vmcnt chunk gate: wait (own oldest loads done) -> fence -> raw barrier.
// N is a literal; sched_barrier stops hipcc hoisting ds_reads above it (rule #18).
#define WAITV(N) do { \
  asm volatile("s_waitcnt vmcnt(" #N ")" ::: "memory"); \
  __builtin_amdgcn_sched_barrier(0); \
  __builtin_amdgcn_s_barrier(); } while(0)

// ---- pack x: [B][NUMS][SEQ] f32 -> xp [SEQ][B][NUMS] bf16 (LDS transpose) ----
__global__ void pack_x_kernel(const float* __restrict__ x, unsigned short* __restrict__ xp){
  __shared__ float tile[64][65];
  const int t0 = blockIdx.x * 64, n0 = blockIdx.y * 64, b = blockIdx.z;
  const int tid = threadIdx.x;
  const int c = tid & 63, r = tid >> 6;
  #pragma unroll
  for (int i = 0; i < 16; i++){
    int n = r + i*4;
    tile[n][c] = x[((size_t)b*NUMS + n0 + n)*SEQn + t0 + c];
  }
  __syncthreads();
  #pragma unroll
  for (int i = 0; i < 16; i++){
    int t = r + i*4;
    xp[((size_t)(t0+t)*Bsz + b)*NUMS + n0 + c] = f2bf(tile[c][t]);
  }
}

// ---- pack W rows into MFMA B-frag order: Wpk[cgg][kof+kst][lane][8] ----
__global__ void pack_w_kernel(const float* __restrict__ W, unsigned short* __restrict__ Wpk,
                              int KST, int row_off, int kstride, int kof){
  const int u = blockIdx.x * blockDim.x + threadIdx.x;
  if (u >= 256*KST*64) return;
  const int lane = u & 63;
  const int kst  = (u >> 6) % KST;
  const int cgg  = (u >> 6) / KST;
  const int nb = cgg >> 2, gate = cgg & 3;
  const int col = gate*Hn + nb*16 + (lane & 15);
  const int kbase = row_off + kst*32 + (lane >> 4)*8;
  unsigned short tmp[8];
  #pragma unroll
  for (int e = 0; e < 8; e++) tmp[e] = f2bf(W[(size_t)(kbase+e)*G4H + col]);
  ((ulonglong2*)Wpk)[(size_t)(cgg*kstride + kof + kst)*64 + lane] = *(const ulonglong2*)tmp;
}

__global__ void zero_kernel(unsigned short* __restrict__ h0, float* __restrict__ c,
                            unsigned* __restrict__ bars){
  int i = blockIdx.x*256 + threadIdx.x;
  if (i < Bsz*Hn){ h0[i] = 0; c[i] = 0.0f; }
  if (i < 2048) bars[i] = 0u;
}

// ---- persistent LSTM layer: W in VGPRs + counted-vmcnt chunk pipeline ----
// grid 256 = 64 nb x 4 mb (1/CU), 512 thr = 8 waves = 4 gates x 2 K-parities.
// Dataflow fact: block (nb,mb) reads h rows of ITS mb only -> the 4 mb-groups are
// fully independent; barrier = 64-arrival counter per (t, mb).
// Per step (L1): [ch0,ch1 prefetched under prev barrier] issue ch2,ch3;
//   WAITV(12) comp0; WAITV(8) comp1; WAITV(4) comp2; WAITV(0) comp3 — loads
//   stay in flight across raw s_barriers (T3/T4), no mid-step vmcnt(0) drain.
// L0: [xb prefetched] issue ch0,ch1; WAITV(4) comp0; WAITV(0) comp1; compXB.
// Bias pre-loaded to registers so per-wave vmcnt counts stay exact.
template<int K1, int S2, int KTOT, int LAYER, bool RING2>
__global__ __launch_bounds__(512, 2)
void persist_kernel(const unsigned short* __restrict__ xpp,
                    unsigned short* __restrict__ hring,
                    unsigned short* __restrict__ h1b,
                    const unsigned short* __restrict__ Wpk,
                    const float* __restrict__ bias,
                    float* __restrict__ cst,
                    float* __restrict__ hf_out,
                    unsigned* __restrict__ bar)
{
  constexpr int KST_TOT = KTOT/32;
  constexpr int HALF = KST_TOT/2;
  constexpr int NFULL = (LAYER == 0) ? 2 : 4;          // full 512-col chunks
  __shared__ unsigned short sa[NFULL][32*512];          // 32KB per chunk buffer
  __shared__ unsigned short sxb[(LAYER == 0) ? 32*128 : 64];  // L0 x-chunk (8KB)
  __shared__ float se[2][4*32*18];                      // epilogue partials (18.4KB)

  const int tid = threadIdx.x;
  const int w = tid >> 6, l = tid & 63;
  const int blk = blockIdx.x;
  const int q = blk >> 3;
  const int nb = (blk & 7)*8 + (q & 7);   // XCD (blk&7) owns 8 consecutive nb
  const int mb = q >> 3;                  // == blk>>6 : the independent group id
  const int ksh = w & 1, cgi = w >> 1;    // K-parity, gate
  const int cgg = nb*4 + cgi;
  const int lrow = l & 15, lg = l >> 4;

  // ---- W -> registers, once ----
  bf16x8 wreg[HALF];
  #pragma unroll
  for (int j = 0; j < HALF; j++)
    wreg[j] = *(const bf16x8*)(Wpk + ((size_t)(cgg*KST_TOT + 2*j + ksh)*64 + l)*8);

  // fixed per-thread epilogue element; c + bias live in registers across steps
  const int erow = tid >> 4, ejj = tid & 15;
  const int R = mb*32 + erow;
  const int J = nb*16 + ejj;
  const size_t idx = (size_t)R*Hn + J;
  float creg = (LAYER == 0) ? 0.f : cst[idx];
  const float bI = bias[0*Hn + J], bF = bias[1*Hn + J];
  const float bO = bias[2*Hn + J], bG = bias[3*Hn + J];

  // 512-col chunk stage: 4 VMEM issues per wave (32 KB total)
  auto stageFull = [&](int ch, const unsigned short* A1p, const unsigned short* A2p){
    unsigned short* dst = sa[ch];
    #pragma unroll
    for (int ii = 0; ii < 4; ii++){
      const int i = ii*8 + w;
      const int s = i*64 + l;
      const int row = s >> 6, uu = s & 63;
      const int ku  = uu ^ (row & 7);
      const int kg  = ch*512 + ku*8;
      const int Rr  = mb*32 + row;
      if (kg < K1){
        const unsigned short* src = A1p + (size_t)Rr*K1 + kg;
        __builtin_amdgcn_global_load_lds(
          (const __attribute__((address_space(1))) void*)src,
          (__attribute__((address_space(3))) void*)&dst[i*512], 16, 0, 0);
      } else {
        const unsigned short* src = A2p + (size_t)Rr*S2 + (kg - K1);
        if constexpr (LAYER == 1 && !RING2){
          __builtin_amdgcn_global_load_lds(   // h1 ping-pong: L3-coherent read
            (const __attribute__((address_space(1))) void*)src,
            (__attribute__((address_space(3))) void*)&dst[i*512], 16, 0, 17);
        } else {
          __builtin_amdgcn_global_load_lds(
            (const __attribute__((address_space(1))) void*)src,
            (__attribute__((address_space(3))) void*)&dst[i*512], 16, 0, 0);
        }
      }
    }
  };
  // L0 x-chunk stage: 1 VMEM issue per wave (8 KB)
  auto stageXB = [&](const unsigned short* A2p){
    const int i = w;
    const int s = i*64 + l;
    const int row = s >> 4, uu = s & 15;
    const int ku  = uu ^ (row & 7);
    const unsigned short* src = A2p + (size_t)(mb*32 + row)*S2 + ku*8;
    __builtin_amdgcn_global_load_lds(
      (const __attribute__((address_space(1))) void*)src,
      (__attribute__((address_space(3))) void*)&sxb[i*512], 16, 0, 0);
  };

  for (int t = 0; t < SEQn; ++t){
    #pragma unroll
    for (int j = 0; j < HALF; j++) asm volatile("" : "+v"(wreg[j]));  // keep W resident

    const unsigned short* A1;
    const unsigned short* A2;
    unsigned short* hout;
    if (LAYER == 0){
      A1   = hring + (size_t)t*BH;                           // h0_{t-1}
      A2   = xpp + (size_t)t*Bsz*NUMS;                       // x_t (static)
      hout = hring + (size_t)(t+1)*BH;
    } else {
      A1   = hring + (size_t)(t+1)*BH;                       // h0_t (prev kernel output)
      A2   = (t == 0) ? (hring + (size_t)SEQn*BH)
                      : (h1b + (size_t)(RING2 ? (t-1) : ((t-1)&1))*BH);
      hout = h1b + (size_t)(RING2 ? t : (t&1))*BH;
    }

    f32x4 acc2[2] = {{0.f,0.f,0.f,0.f},{0.f,0.f,0.f,0.f}};

    // ---- issue this step's remaining loads (ch0/ch1 or xb came from prev barrier) ----
    if constexpr (LAYER == 1){
      if (t == 0){ stageFull(0, A1, A2); stageFull(1, A1, A2); }
      stageFull(2, A1, A2); stageFull(3, A1, A2);
    } else {
      if (t == 0) stageXB(A2);
      stageFull(0, A1, A2); stageFull(1, A1, A2);
    }

    // ---- compute chunks under counted waits ----
    auto comp = [&](auto CHC){
      constexpr int ch = decltype(CHC)::value;
      const unsigned short* abase = sa[ch];
      #pragma unroll
      for (int ksl = 0; ksl < 8; ksl++){
        const int klocal = ksl*2 + ksh;
        const int unit = klocal*4 + lg;
        bf16x8 af0 = *(const bf16x8*)&abase[((lrow     )*64 + (unit ^ (lrow & 7)))*8];
        bf16x8 af1 = *(const bf16x8*)&abase[((lrow + 16)*64 + (unit ^ (lrow & 7)))*8];
        acc2[0] = __builtin_amdgcn_mfma_f32_16x16x32_bf16(af0, wreg[ch*8 + ksl], acc2[0], 0, 0, 0);
        acc2[1] = __builtin_amdgcn_mfma_f32_16x16x32_bf16(af1, wreg[ch*8 + ksl], acc2[1], 0, 0, 0);
      }
    };

    if constexpr (LAYER == 1){
      WAITV(12); comp(IC<0>{});
      WAITV(8);  comp(IC<1>{});
      WAITV(4);  comp(IC<2>{});
      WAITV(0);  comp(IC<3>{});
    } else {
      WAITV(4);  comp(IC<0>{});          // oldest 5 = xb + ch0 retired
      WAITV(0);  comp(IC<1>{});
      #pragma unroll
      for (int ksl = 0; ksl < 2; ksl++){ // x-chunk (already complete at WAITV(4))
        const int klocal = ksl*2 + ksh;
        const int unit = klocal*4 + lg;
        bf16x8 af0 = *(const bf16x8*)&sxb[((lrow     )*16 + (unit ^ (lrow & 7)))*8];
        bf16x8 af1 = *(const bf16x8*)&sxb[((lrow + 16)*16 + (unit ^ (lrow & 7)))*8];
        acc2[0] = __builtin_amdgcn_mfma_f32_16x16x32_bf16(af0, wreg[16 + ksl], acc2[0], 0, 0, 0);
        acc2[1] = __builtin_amdgcn_mfma_f32_16x16x32_bf16(af1, wreg[16 + ksl], acc2[1], 0, 0, 0);
      }
    }

    {   // partials -> LDS: [ksh][gate*32 + row][col]
      #pragma unroll
      for (int mi = 0; mi < 2; mi++)
        #pragma unroll
        for (int r = 0; r < 4; r++){
          const int row2 = mi*16 + lg*4 + r;
          se[ksh][(cgi*32 + row2)*18 + lrow] = acc2[mi][r];
        }
    }
    __syncthreads();
    {
      float zi = se[0][(0*32+erow)*18 + ejj] + se[1][(0*32+erow)*18 + ejj] + bI;
      float zf = se[0][(1*32+erow)*18 + ejj] + se[1][(1*32+erow)*18 + ejj] + bF;
      float zo = se[0][(2*32+erow)*18 + ejj] + se[1][(2*32+erow)*18 + ejj] + bO;
      float zg = se[0][(3*32+erow)*18 + ejj] + se[1][(3*32+erow)*18 + ejj] + bG;
      const float gi = 1.f/(1.f + __expf(-zi));
      const float gf = 1.f/(1.f + __expf(-zf));
      const float go = 1.f/(1.f + __expf(-zo));
      const float gg = tanhf(zg);
      creg = gf * creg + gi * gg;
      const float hn = go * tanhf(creg);
      // publish h at agent scope (sc1 -> L3), packed 2x bf16 per dword
      const unsigned hu   = (unsigned)f2bf(hn);
      const unsigned mate = (unsigned)__shfl_xor((int)hu, 1);
      if ((l & 1) == 0){
        const unsigned pk = hu | (mate << 16);
        __hip_atomic_store((unsigned*)(hout + idx), pk,
                           __ATOMIC_RELAXED, __HIP_MEMORY_SCOPE_AGENT);
      }
      if (t == SEQn-1){
        cst[idx] = creg;                 // layer handoff / final output (kernel boundary)
        if (LAYER == 1) hf_out[idx] = hn;
      }
    }

    if (t + 1 < SEQn){
      // ---- mb-group barrier (64 arrivals) with in-barrier prefetch ----
      __syncthreads();                   // drains vmcnt: publish at L3; se reads done
      if (tid == 0)
        __hip_atomic_fetch_add(&bar[t*4 + mb], 1u,
                               __ATOMIC_RELAXED, __HIP_MEMORY_SCOPE_AGENT);
      if constexpr (LAYER == 1){
        // next step's h0 chunks: produced by the PREVIOUS kernel -> stable now
        const unsigned short* A1n = hring + (size_t)(t+2)*BH;
        stageFull(0, A1n, A1n);
        stageFull(1, A1n, A1n);
      } else {
        stageXB(xpp + (size_t)(t+1)*Bsz*NUMS);   // x static
      }
      if (tid == 0){
        while (__hip_atomic_load(&bar[t*4 + mb], __ATOMIC_RELAXED,
                                 __HIP_MEMORY_SCOPE_AGENT) < 64u)
          __builtin_amdgcn_s_sleep(1);
      }
      __builtin_amdgcn_s_barrier();      // raw: prefetch stays in flight
    }
  }
}

// ---- final FC + copy h,c to d_out ----
__global__ __launch_bounds__(256)
void fc_out_kernel(const float* __restrict__ hf, const float* __restrict__ cst,
                   const float* __restrict__ fcw, const float* __restrict__ fcb,
                   float* __restrict__ dout){
  __shared__ float hrow[Hn];
  const int b = blockIdx.x, tid = threadIdx.x;
  for (int i = tid; i < Hn; i += 256) hrow[i] = hf[(size_t)b*Hn + i];
  __syncthreads();
  if (tid < PRED){
    float a = fcb[tid];
    for (int k = 0; k < Hn; k++) a += hrow[k] * fcw[(size_t)k*PRED + tid];
    dout[(size_t)b*PRED + tid] = tanhf(a);
  }
  for (int i = tid; i < Hn; i += 256){
    dout[Bsz*PRED + (size_t)b*Hn + i] = hf[(size_t)b*Hn + i];
    dout[Bsz*PRED + (size_t)Bsz*Hn + (size_t)b*Hn + i] = cst[(size_t)b*Hn + i];
  }
}

extern "C" void kernel_launch(void* const* d_in, const int* in_sizes, int n_in,
                              void* d_out, int out_size, void* d_ws, size_t ws_size,
                              hipStream_t stream){
  const float* x   = (const float*)d_in[0];
  const float* W0  = (const float*)d_in[1];
  const float* b0  = (const float*)d_in[2];
  const float* W1  = (const float*)d_in[3];
  const float* b1  = (const float*)d_in[4];
  const float* fcw = (const float*)d_in[5];
  const float* fcb = (const float*)d_in[6];
  float* dout = (float*)d_out;

  char* p = (char*)d_ws;
  auto alloc = [&](size_t bytes)->void*{
    void* r = (void*)p; p += (bytes + 255) & ~(size_t)255; return r;
  };
  // base footprint ~103.5 MB (proven); +67 MB h1 ring only if workspace allows
  unsigned short* xp   = (unsigned short*)alloc((size_t)SEQn*Bsz*NUMS*2);      // 8.4 MB
  unsigned short* Wpk0 = (unsigned short*)alloc((size_t)256*36*64*8*2);        // 9.4 MB
  unsigned short* Wpk1 = (unsigned short*)alloc((size_t)256*64*64*8*2);        // 16.8 MB
  unsigned short* H0   = (unsigned short*)alloc((size_t)(SEQn+1)*BH*2);        // 67.4 MB
  float* cst = (float*)alloc((size_t)BH*4);                                    // 0.5 MB
  float* hf  = (float*)alloc((size_t)BH*4);                                    // 0.5 MB
  unsigned* bars = (unsigned*)alloc((size_t)2048*sizeof(unsigned));            // 8 KB

  const bool big = ws_size >= (size_t)176*1024*1024;   // room for write-once h1 ring?
  unsigned short* h1b;
  if (big) h1b = (unsigned short*)alloc((size_t)SEQn*BH*2);                    // 67.1 MB
  else     h1b = (unsigned short*)alloc((size_t)2*BH*2);                       // 0.5 MB

  pack_x_kernel<<<dim3(SEQn/64, NUMS/64, Bsz), dim3(256), 0, stream>>>(x, xp);
  // W0 packed K order: [h rows 128..1151 -> kst 0..31][x rows 0..127 -> kst 32..35]
  pack_w_kernel<<<dim3((256*32*64 + 255)/256), dim3(256), 0, stream>>>(W0, Wpk0, 32, 128, 36, 0);
  pack_w_kernel<<<dim3((256*4*64  + 255)/256), dim3(256), 0, stream>>>(W0, Wpk0,  4,   0, 36, 32);
  // W1: rows 0..1023 = h0-part, 1024..2047 = h1-part (natural order)
  pack_w_kernel<<<dim3((256*64*64 + 255)/256), dim3(256), 0, stream>>>(W1, Wpk1, 64, 0, 64, 0);
  zero_kernel<<<dim3((Bsz*Hn + 255)/256), dim3(256), 0, stream>>>(H0, cst, bars);

  // layer 0: ONE persistent launch, 256 grid-barriered steps (K = [h 1024 | x 128])
  persist_kernel<1024, NUMS, 1152, 0, false><<<dim3(GN), dim3(512), 0, stream>>>(
      xp, H0, nullptr, Wpk0, b0, cst, nullptr, bars);

  // layer 1: ONE persistent launch (K = [h0 1024 | h1 1024])
  if (big){
    persist_kernel<1024, Hn, 2048, 1, true><<<dim3(GN), dim3(512), 0, stream>>>(
        nullptr, H0, h1b, Wpk1, b1, cst, hf, bars + 1024);
  } else {
    persist_kernel<1024, Hn, 2048, 1, false><<<dim3(GN), dim3(512), 0, stream>>>(
        nullptr, H0, h1b, Wpk1, b1, cst, hf, bars + 1024);
  }

  fc_out_kernel<<<dim3(Bsz), dim3(256), 0, stream>>>(hf, cst, fcw, fcb, dout);
}